// Round 10
// baseline (484.060 us; speedup 1.0000x reference)
//
#include <hip/hip_runtime.h>

typedef _Float16 f16x8 __attribute__((ext_vector_type(8)));
typedef float    f32x4 __attribute__((ext_vector_type(4)));

constexpr int BATCH = 2048;
constexpr int SEQ   = 512;
constexpr int H     = 50;
constexpr int NB    = 8;     // batch per block -> 256 blocks = 1 per CU
constexpr int NT    = 896;   // 14 waves: 7 L0-group + 7 L1-group
constexpr int KQ    = 7;     // panel k-chunks of 32 (K=224)
constexpr int SLOT  = KQ * 64 * 8;   // halfs per ring slot (3584 = 7 KB)
constexpr int R     = 4;     // ring depth (steps)

__device__ __forceinline__ float fexp2(float x) { return __builtin_amdgcn_exp2f(x); }
__device__ __forceinline__ float frcp(float x)  { return __builtin_amdgcn_rcpf(x); }
__device__ __forceinline__ _Float16 f16hi(float w) { return (_Float16)w; }
__device__ __forceinline__ _Float16 f16lo(float w) {
    _Float16 h = (_Float16)w; return (_Float16)(w - (float)h);
}
__device__ __forceinline__ int baddr(int k, int n) {   // halfs; k<224, n<16
    return (((k >> 5) * 64) + (((k >> 3) & 3) * 16) + n) * 8 + (k & 7);
}
union H2U { unsigned u; _Float16 h[2]; };

constexpr float K1 = 1.4426950408889634f;   // log2(e)
constexpr float K2 = 2.8853900817779268f;   // 2*log2(e)

// Ring slot k-map (r9 layout): [0,100) h1 unit j=k>>1 (odd=lo); 100,101 x rows
// (NEVER written -> stay 0; x applied as scalar FMA in L0 combine); [102,112)
// pad; [112,212) h2 unit j=(k-112)>>1; [212,224) pad.  Columns 8-15 duplicate
// batches 0-7.  GATE PERM (r9): tile t phys row w <-> j = 4t+(w>>2), gate w&3.
//
// WAVE SPECIALIZATION, NO BARRIER IN LOOP:
//  L0 group (7 waves): step s: needs cnt0>=7s (own group done s-1) and
//    cnt1>=7(s-3) (L1 finished step s-4 -> slot s%R's old h1 fully consumed).
//    Reads chunks 0..3 of slot (s-1)%R  [h2/x rows there hit zero A-rows ->
//    torn concurrent h2 writes are harmless: finite*0].  Writes h1(s) ->
//    slot s%R, then cnt0 += 1 per wave (release).
//  L1 group (7 waves): step s: needs cnt1>=7s (own group done s-1, so
//    h2(s-1) -> slot s%R complete) and cnt0>=7(s+1) (h1(s) complete).
//    Reads chunks 0..6 of slot s%R.  Writes h2(s) -> slot (s+1)%R
//    (s=511 -> sH2f), then cnt1 += 1 (release).
//  Slot-collision proof: L0 writer of slot s%R vs L1 reader of slot s'%R with
//  s' = s-4: gated by cnt1>=7(s-3) = L1 completed s-4.  L1 writer slot
//  (s+1)%R vs L0 reader slot (s'-1)%R, s' = s+2..: only zero-A rows. OK.

__global__ __launch_bounds__(NT, 4) void lstm2_ws(
    const float* __restrict__ x,
    const float* __restrict__ Wih0, const float* __restrict__ Whh0,
    const float* __restrict__ bih0, const float* __restrict__ bhh0,
    const float* __restrict__ Wih1, const float* __restrict__ Whh1,
    const float* __restrict__ bih1, const float* __restrict__ bhh1,
    const float* __restrict__ fcW,  const float* __restrict__ fcb,
    float* __restrict__ out)
{
    __shared__ _Float16 sRing[R][SLOT];   // 28 KB
    __shared__ float    sX32[SEQ * NB];   // 16 KB raw f32 x
    __shared__ float    sH2f[H * NB];
    __shared__ int      cnt0, cnt1;

    const int t    = threadIdx.x;
    const int wave = t >> 6, lane = t & 63;
    const int quad = lane >> 4, nn = lane & 15;
    const int bbase = blockIdx.x * NB;

    for (int i = t; i < R * SLOT; i += NT) ((_Float16*)sRing)[i] = (_Float16)0.f;
    for (int i = t; i < NB * SEQ; i += NT) {
        const int b = i >> 9, s = i & (SEQ - 1);
        sX32[s * NB + b] = x[(bbase + b) * SEQ + s];
    }
    if (t == 0) { cnt0 = 0; cnt1 = 0; }

    // role split interleaved so each SIMD gets a mix of both groups
    const bool isL0 = (wave < 4) || (wave >= 8 && wave < 11);
    const int  gw   = isL0 ? (wave < 4 ? wave : wave - 4)
                           : (wave < 8 ? wave - 4 : wave - 7);

    // per-lane combine identity: lanes nn<8 combine tile 2gw, nn>=8 tile 2gw+1
    const int  colb = nn & 7;
    const int  jC   = 8 * gw + ((nn >= 8) ? 4 : 0) + quad;
    const bool wrOK = (jC < H);

    __syncthreads();   // the ONLY block barrier

    if (isL0) {
        // ---- A-frags: Whh0 only (x rows zero), tiles 2gw, 2gw+1 ----
        f16x8 a[2][4]; f32x4 bv[2];
        #pragma unroll
        for (int i = 0; i < 2; ++i) {
            const int  ti   = 2 * gw + i;
            const int  jr   = ti * 4 + (nn >> 2);
            const int  gate = nn & 3;
            const bool rv   = (jr < H);
            const int  lrow = gate * H + jr;
            #pragma unroll
            for (int q = 0; q < 4; ++q) {
                #pragma unroll
                for (int j8 = 0; j8 < 8; ++j8) {
                    const int k = q * 32 + quad * 8 + j8;
                    _Float16 v = (_Float16)0.f;
                    if (rv && k < 100) {
                        float w = Whh0[lrow * H + (k >> 1)];
                        v = (k & 1) ? f16lo(w) : f16hi(w);
                    }
                    a[i][q][j8] = v;
                }
            }
            const int jq = ti * 4 + quad;
            #pragma unroll
            for (int r = 0; r < 4; ++r)
                bv[i][r] = (jq < H) ? (bih0[r * H + jq] + bhh0[r * H + jq]) : 0.f;
        }
        float wx[4];
        #pragma unroll
        for (int r = 0; r < 4; ++r) wx[r] = wrOK ? Wih0[r * H + jC] : 0.f;

        const int uW0 = baddr(2 * jC, colb)     >> 1;
        const int uW1 = baddr(2 * jC, colb + 8) >> 1;
        float c = 0.f;

        #pragma unroll 1
        for (int s = 0; s < SEQ; ++s) {
            const int tgt0 = 7 * s, tgt1 = 7 * (s - 3);
            while (__hip_atomic_load(&cnt0, __ATOMIC_ACQUIRE, __HIP_MEMORY_SCOPE_WORKGROUP) < tgt0 ||
                   __hip_atomic_load(&cnt1, __ATOMIC_ACQUIRE, __HIP_MEMORY_SCOPE_WORKGROUP) < tgt1)
                __builtin_amdgcn_s_sleep(1);

            const _Float16* br = sRing[(s + 3) & 3];   // slot (s-1)%R
            f16x8 bq[4];
            #pragma unroll
            for (int q = 0; q < 4; ++q)
                bq[q] = *(const f16x8*)&br[(q * 64 + lane) * 8];

            f32x4 aA = bv[0], aB = bv[1];
            #pragma unroll
            for (int q = 0; q < 4; ++q) {
                aA = __builtin_amdgcn_mfma_f32_16x16x32_f16(a[0][q], bq[q], aA, 0, 0, 0);
                aB = __builtin_amdgcn_mfma_f32_16x16x32_f16(a[1][q], bq[q], aB, 0, 0, 0);
            }
            f32x4 g;
            #pragma unroll
            for (int r = 0; r < 4; ++r) g[r] = (nn >= 8) ? aB[r] : aA[r];
            const float xv = sX32[s * NB + colb];
            #pragma unroll
            for (int r = 0; r < 4; ++r) g[r] = fmaf(wx[r], xv, g[r]);

            float Ei = fexp2(-K1 * g[0]);
            float Ef = fexp2(-K1 * g[1]);
            float Eg = fexp2(-K2 * fabsf(g[2]));
            float Eo = fexp2(-K1 * g[3]);
            float it = copysignf((1.f - Eg) * frcp((1.f + Ei) * (1.f + Eg)), g[2]);
            c = frcp(1.f + Ef) * c + it;
            float Ec = fexp2(-K2 * fabsf(c));
            float h  = copysignf((1.f - Ec) * frcp((1.f + Eo) * (1.f + Ec)), c);

            if (wrOK) {
                _Float16 hh = f16hi(h);
                H2U p; p.h[0] = hh; p.h[1] = (_Float16)(h - (float)hh);
                unsigned* bw = (unsigned*)sRing[s & 3];
                bw[uW0] = p.u; bw[uW1] = p.u;
            }
            if (lane == 0)
                __hip_atomic_fetch_add(&cnt0, 1, __ATOMIC_RELEASE, __HIP_MEMORY_SCOPE_WORKGROUP);
        }
    } else {
        // ---- A-frags: Wih1 (k<100) + Whh1 (112<=k<212), tiles 2gw, 2gw+1 ----
        f16x8 a[2][KQ]; f32x4 bv[2];
        #pragma unroll
        for (int i = 0; i < 2; ++i) {
            const int  ti   = 2 * gw + i;
            const int  jr   = ti * 4 + (nn >> 2);
            const int  gate = nn & 3;
            const bool rv   = (jr < H);
            const int  lrow = gate * H + jr;
            #pragma unroll
            for (int q = 0; q < KQ; ++q) {
                #pragma unroll
                for (int j8 = 0; j8 < 8; ++j8) {
                    const int k = q * 32 + quad * 8 + j8;
                    _Float16 v = (_Float16)0.f;
                    if (rv) {
                        if (k < 100) {
                            float w = Wih1[lrow * H + (k >> 1)];
                            v = (k & 1) ? f16lo(w) : f16hi(w);
                        } else if (k >= 112 && k < 212) {
                            float w = Whh1[lrow * H + ((k - 112) >> 1)];
                            v = (k & 1) ? f16lo(w) : f16hi(w);
                        }
                    }
                    a[i][q][j8] = v;
                }
            }
            const int jq = ti * 4 + quad;
            #pragma unroll
            for (int r = 0; r < 4; ++r)
                bv[i][r] = (jq < H) ? (bih1[r * H + jq] + bhh1[r * H + jq]) : 0.f;
        }

        const int uW0 = baddr(112 + 2 * jC, colb)     >> 1;
        const int uW1 = baddr(112 + 2 * jC, colb + 8) >> 1;
        float c = 0.f;

        #pragma unroll 1
        for (int s = 0; s < SEQ; ++s) {
            const int tgt1 = 7 * s, tgt0 = 7 * (s + 1);
            while (__hip_atomic_load(&cnt0, __ATOMIC_ACQUIRE, __HIP_MEMORY_SCOPE_WORKGROUP) < tgt0 ||
                   __hip_atomic_load(&cnt1, __ATOMIC_ACQUIRE, __HIP_MEMORY_SCOPE_WORKGROUP) < tgt1)
                __builtin_amdgcn_s_sleep(1);

            const _Float16* br = sRing[s & 3];
            f16x8 bq[KQ];
            #pragma unroll
            for (int q = 0; q < KQ; ++q)
                bq[q] = *(const f16x8*)&br[(q * 64 + lane) * 8];

            f32x4 aA = bv[0], aB = bv[1];
            #pragma unroll
            for (int q = 0; q < KQ; ++q) {
                aA = __builtin_amdgcn_mfma_f32_16x16x32_f16(a[0][q], bq[q], aA, 0, 0, 0);
                aB = __builtin_amdgcn_mfma_f32_16x16x32_f16(a[1][q], bq[q], aB, 0, 0, 0);
            }
            f32x4 g;
            #pragma unroll
            for (int r = 0; r < 4; ++r) g[r] = (nn >= 8) ? aB[r] : aA[r];

            float Ei = fexp2(-K1 * g[0]);
            float Ef = fexp2(-K1 * g[1]);
            float Eg = fexp2(-K2 * fabsf(g[2]));
            float Eo = fexp2(-K1 * g[3]);
            float it = copysignf((1.f - Eg) * frcp((1.f + Ei) * (1.f + Eg)), g[2]);
            c = frcp(1.f + Ef) * c + it;
            float Ec = fexp2(-K2 * fabsf(c));
            float h  = copysignf((1.f - Ec) * frcp((1.f + Eo) * (1.f + Ec)), c);

            if (wrOK) {
                if (s == SEQ - 1) {
                    sH2f[jC * NB + colb] = h;
                } else {
                    _Float16 hh = f16hi(h);
                    H2U p; p.h[0] = hh; p.h[1] = (_Float16)(h - (float)hh);
                    unsigned* bw = (unsigned*)sRing[(s + 1) & 3];
                    bw[uW0] = p.u; bw[uW1] = p.u;
                }
            }
            if (lane == 0)
                __hip_atomic_fetch_add(&cnt1, 1, __ATOMIC_RELEASE, __HIP_MEMORY_SCOPE_WORKGROUP);
        }

        // ---- FC epilogue on L1 wave gw==0 ----
        if (gw == 0) {
            while (__hip_atomic_load(&cnt1, __ATOMIC_ACQUIRE, __HIP_MEMORY_SCOPE_WORKGROUP) < 7 * SEQ)
                __builtin_amdgcn_s_sleep(1);
            if (lane < NB) {
                float sum = fcb[0];
                #pragma unroll
                for (int jx = 0; jx < H; ++jx) sum += fcW[jx] * sH2f[jx * NB + lane];
                out[bbase + lane] = sum;
            }
        }
    }
}

extern "C" void kernel_launch(void* const* d_in, const int* in_sizes, int n_in,
                              void* d_out, int out_size, void* d_ws, size_t ws_size,
                              hipStream_t stream)
{
    const float* x    = (const float*)d_in[0];
    const float* Wih0 = (const float*)d_in[1];
    const float* Whh0 = (const float*)d_in[2];
    const float* bih0 = (const float*)d_in[3];
    const float* bhh0 = (const float*)d_in[4];
    const float* Wih1 = (const float*)d_in[5];
    const float* Whh1 = (const float*)d_in[6];
    const float* bih1 = (const float*)d_in[7];
    const float* bhh1 = (const float*)d_in[8];
    const float* fcW  = (const float*)d_in[9];
    const float* fcb  = (const float*)d_in[10];

    lstm2_ws<<<BATCH / NB, NT, 0, stream>>>(
        x, Wih0, Whh0, bih0, bhh0, Wih1, Whh1, bih1, bhh1, fcW, fcb,
        (float*)d_out);
}

// Round 11
// 321.672 us; speedup vs baseline: 1.5048x; 1.5048x over previous
//
#include <hip/hip_runtime.h>

typedef _Float16 f16x8 __attribute__((ext_vector_type(8)));
typedef float    f32x4 __attribute__((ext_vector_type(4)));

constexpr int BATCH = 2048;
constexpr int SEQ   = 512;
constexpr int H     = 50;
constexpr int NB    = 8;     // batch per block -> 256 blocks = 1 per CU
constexpr int NT    = 1024;  // 16 waves, 4 per SIMD
constexpr int KQ    = 4;     // panel k-chunks of 32 (K=128)
constexpr int PSZ   = KQ * 64 * 8;   // panel halfs (2048 = 4 KB)

__device__ __forceinline__ float fexp2(float x) { return __builtin_amdgcn_exp2f(x); }
__device__ __forceinline__ float frcp(float x)  { return __builtin_amdgcn_rcpf(x); }
__device__ __forceinline__ _Float16 f16hi(float w) { return (_Float16)w; }
__device__ __forceinline__ _Float16 f16lo(float w) {
    _Float16 h = (_Float16)w; return (_Float16)(w - (float)h);
}
// B-panel frag-linear address (halfs) for value (k, n), k<128, n<16
__device__ __forceinline__ int baddr(int k, int n) {
    return (((k >> 5) * 64) + (((k >> 3) & 3) * 16) + n) * 8 + (k & 7);
}
union H2U { unsigned u; _Float16 h[2]; };

constexpr float K1 = 1.4426950408889634f;   // log2(e)
constexpr float K2 = 2.8853900817779268f;   // 2*log2(e)

// Panel k-map (HI-ONLY f16 h, 4 chunks):
//   k in [0,50):   h1 unit j=k (single f16)
//   k 50,51:       x_hi, x_lo  (x exact: A rows hold wx_hi/wx_lo)
//   k [52,64):     zero pad
//   k [64,114):    h2 unit j=k-64 (single f16)
//   k [114,128):   zero pad
// Columns 8..15 duplicate batches 0..7 (kills the L0/L1 merge bpermute).
// GATE PERM (r9): tile m phys row w <-> jj = 4m+(w>>2), gate w&3; after MFMA
// lane (quad,nn) reg r = gate r of hidden jj = 4m+quad, batch nn -> combine
// runs in-register in the owning lane (lanes nn<8: L0; nn>=8: L1).
// Schedule (1 barrier/step): iter s reads sB[s&1] = {h1(s-1), x(s), h2(s-2)},
// writes sB[(s+1)&1] = {h1(s), x(s+1), h2(s-1)}.  Unroll-2 -> compile-time
// panel pointers; edges (s=0,511,512) peeled.
// Precision: w,h products carry ~2*2^-11 rel error (vs exact in r9's hi/lo
// scheme); biases/x exact; c-recurrence in f32.  Predicted absmax <~1.3e-3.

__global__ __launch_bounds__(NT, 4) void lstm2_hi(
    const float* __restrict__ x,
    const float* __restrict__ Wih0, const float* __restrict__ Whh0,
    const float* __restrict__ bih0, const float* __restrict__ bhh0,
    const float* __restrict__ Wih1, const float* __restrict__ Whh1,
    const float* __restrict__ bih1, const float* __restrict__ bhh1,
    const float* __restrict__ fcW,  const float* __restrict__ fcb,
    float* __restrict__ out)
{
    __shared__ _Float16 sB[2][PSZ];     // double-buffered panel, 8 KB
    __shared__ unsigned sXu[SEQ * NB];  // pre-split x (hi,lo), 16 KB
    __shared__ float    sH2f[H * NB];   // final h2

    const int t    = threadIdx.x;
    const int wave = t >> 6, lane = t & 63;
    const int quad = lane >> 4, nn = lane & 15;
    const int bbase = blockIdx.x * NB;

    // zero both panels (pads must stay 0 forever)
    for (int i = t; i < 2 * PSZ; i += NT) ((_Float16*)sB)[i] = (_Float16)0.f;

    // ---- pre-stage ALL x as packed f16 hi/lo pairs (coalesced) ----
    for (int i = t; i < NB * SEQ; i += NT) {
        const int b = i >> 9, s = i & (SEQ - 1);
        float xv = x[(bbase + b) * SEQ + s];
        H2U p; p.h[0] = f16hi(xv); p.h[1] = f16lo(xv);
        sXu[s * NB + b] = p.u;
    }

    // ---- constant A-fragments; wave w owns tile m = w (13 active waves) ----
    const bool mmv = (wave < 13);
    f16x8 a0[2];       // L0: chunks 0..1 (K=64)
    f16x8 a1[KQ];      // L1: chunks 0..3 (K=128)
    f32x4 b0v = {0,0,0,0}, b1v = {0,0,0,0};
    if (mmv) {
        const int  m    = wave;
        const int  jr   = m * 4 + (nn >> 2);     // hidden unit of A phys row nn
        const int  gate = nn & 3;
        const bool rv   = (jr < H);
        const int  lrow = gate * H + jr;         // logical W row
        #pragma unroll
        for (int q = 0; q < 2; ++q) {
            #pragma unroll
            for (int j = 0; j < 8; ++j) {
                const int k = q * 32 + quad * 8 + j;
                _Float16 v = (_Float16)0.f;
                if (rv) {
                    if      (k < 50)   v = (_Float16)Whh0[lrow * H + k];
                    else if (k == 50)  v = f16hi(Wih0[lrow]);
                    else if (k == 51)  v = f16lo(Wih0[lrow]);
                }
                a0[q][j] = v;
            }
        }
        #pragma unroll
        for (int q = 0; q < KQ; ++q) {
            #pragma unroll
            for (int j = 0; j < 8; ++j) {
                const int k = q * 32 + quad * 8 + j;
                _Float16 v = (_Float16)0.f;
                if (rv) {
                    if      (k < 50)              v = (_Float16)Wih1[lrow * H + k];
                    else if (k >= 64 && k < 114)  v = (_Float16)Whh1[lrow * H + (k - 64)];
                }
                a1[q][j] = v;
            }
        }
        const int jq = m * 4 + quad;
        #pragma unroll
        for (int r = 0; r < 4; ++r) {
            const bool bv = (jq < H);
            b0v[r] = bv ? (bih0[r * H + jq] + bhh0[r * H + jq]) : 0.f;
            b1v[r] = bv ? (bih1[r * H + jq] + bhh1[r * H + jq]) : 0.f;
        }
    }

    // per-lane combine identity
    const int  jj   = wave * 4 + quad;        // hidden unit (valid < 50)
    const bool hiH  = (nn >= 8);              // hi lanes combine L1
    const int  col  = nn & 7;                 // batch
    const int  kb   = hiH ? (64 + jj) : jj;   // this lane's h row in the panel
    const int  wH0  = baddr(kb, col);         // half slot, column copy 0
    const int  wH1  = baddr(kb, col + 8);     // half slot, column copy 1
    const bool wrOK = mmv && (jj < H);
    float c = 0.f;                            // c0 (lo lanes) or c1 (hi lanes)

    // x-staging lane constants (wave 15, lanes 0..15 cover both copies)
    const int xcol = lane & 7;
    const int xad  = baddr(50, (lane & 7) + 8 * ((lane >> 3) & 1)) >> 1; // u32 idx

    __syncthreads();
    if (t < 16)                               // x(0), both column copies
        ((unsigned*)sB[0])[baddr(50, (t & 7) + 8 * (t >> 3)) >> 1] = sXu[t & 7];
    __syncthreads();

    auto body = [&](int s, const _Float16* __restrict__ br,
                    _Float16* __restrict__ bw,
                    bool doL0, bool doL1, bool doX, bool last) {
        if (mmv) {
            f16x8 bq[KQ];
            #pragma unroll
            for (int q = 0; q < KQ; ++q)
                bq[q] = *(const f16x8*)&br[(q * 64 + lane) * 8];

            f32x4 g0 = b0v;
            #pragma unroll
            for (int q = 0; q < 2; ++q)
                g0 = __builtin_amdgcn_mfma_f32_16x16x32_f16(a0[q], bq[q], g0, 0, 0, 0);
            f32x4 g1 = b1v;
            #pragma unroll
            for (int q = 0; q < KQ; ++q)
                g1 = __builtin_amdgcn_mfma_f32_16x16x32_f16(a1[q], bq[q], g1, 0, 0, 0);

            f32x4 g;
            #pragma unroll
            for (int r = 0; r < 4; ++r) g[r] = hiH ? g1[r] : g0[r];

            const bool act = hiH ? doL1 : doL0;
            if (act) {
                float Ei = fexp2(-K1 * g[0]);
                float Ef = fexp2(-K1 * g[1]);
                float Eg = fexp2(-K2 * fabsf(g[2]));
                float Eo = fexp2(-K1 * g[3]);
                float it = copysignf((1.f - Eg) * frcp((1.f + Ei) * (1.f + Eg)), g[2]);
                c = frcp(1.f + Ef) * c + it;
                float Ec = fexp2(-K2 * fabsf(c));
                float h  = copysignf((1.f - Ec) * frcp((1.f + Eo) * (1.f + Ec)), c);
                if (wrOK) {
                    if (last && hiH) {
                        sH2f[jj * NB + col] = h;        // h2(511) for the FC
                    } else {
                        _Float16 hh = (_Float16)h;
                        bw[wH0] = hh;                   // column copy 0
                        bw[wH1] = hh;                   // column copy 1
                    }
                }
            }
        } else if (doX && wave == 15 && lane < 16) {
            ((unsigned*)bw)[xad] = sXu[(s + 1) * NB + xcol];
        }
        __syncthreads();   // the ONLY barrier per step
    };

    body(0, sB[0], sB[1], true, false, true, false);
    #pragma unroll 1
    for (int i = 0; i < 255; ++i) {
        body(2 * i + 1, sB[1], sB[0], true, true, true, false);
        body(2 * i + 2, sB[0], sB[1], true, true, true, false);
    }
    body(511, sB[1], sB[0], true, true, false, false);
    body(512, sB[0], sB[1], false, true, false, true);

    // ---- FC epilogue: out[b] = fcW . h2_last[b] + fcb ----
    if (t < NB) {
        float sum = fcb[0];
        #pragma unroll
        for (int jx = 0; jx < H; ++jx) sum += fcW[jx] * sH2f[jx * NB + t];
        out[bbase + t] = sum;
    }
}

extern "C" void kernel_launch(void* const* d_in, const int* in_sizes, int n_in,
                              void* d_out, int out_size, void* d_ws, size_t ws_size,
                              hipStream_t stream)
{
    const float* x    = (const float*)d_in[0];
    const float* Wih0 = (const float*)d_in[1];
    const float* Whh0 = (const float*)d_in[2];
    const float* bih0 = (const float*)d_in[3];
    const float* bhh0 = (const float*)d_in[4];
    const float* Wih1 = (const float*)d_in[5];
    const float* Whh1 = (const float*)d_in[6];
    const float* bih1 = (const float*)d_in[7];
    const float* bhh1 = (const float*)d_in[8];
    const float* fcW  = (const float*)d_in[9];
    const float* fcb  = (const float*)d_in[10];

    lstm2_hi<<<BATCH / NB, NT, 0, stream>>>(
        x, Wih0, Whh0, bih0, bhh0, Wih1, Whh1, bih1, bhh1, fcW, fcb,
        (float*)d_out);
}